// Round 4
// baseline (1056.684 us; speedup 1.0000x reference)
//
#include <hip/hip_runtime.h>
#include <stdint.h>

// AttractorDynamics: sigma = iterate(tanh(drive + (sigma @ J^T)/tau), 10)
// B=16384, M=1024, A=512, tau=0.1, sigma0=0.
// R6: force the 256-VGPR budget via the LDS-occupancy coupling.
//  - R4/R5 post-mortem: BOTH __launch_bounds__(512,2) and
//    amdgpu_waves_per_eu(2,2) were ignored (VGPR_Count stayed 128; spill
//    traffic unchanged). The allocator's budget tracks STATIC-LDS-implied
//    occupancy: 64KB LDS -> 2 blocks/CU -> 4 waves/EU -> 128 VGPRs.
//  - Fix: sigma DOUBLE-BUFFERED in LDS (2 x 64KB = 128KB static) -> only
//    1 block/CU fits -> 2 waves/EU -> 256-VGPR budget by the compiler's
//    own arithmetic. Grid is already 256 = #CUs, so nothing is lost.
//  - Bonus: ping-pong buffers need only ONE barrier per step (writes go to
//    the idle buffer; "done reading" + "writes visible" merge).
// drive_kernel / split_kernel unchanged.

#define B_DIM 16384
#define M_DIM 1024
#define A_DIM 512

typedef short bf16x8 __attribute__((ext_vector_type(8)));
typedef float f32x4 __attribute__((ext_vector_type(4)));

__device__ __forceinline__ unsigned short f2bf(float f) {
  unsigned int u = __float_as_uint(f);
  unsigned int r = (u + 0x7FFFu + ((u >> 16) & 1u)) >> 16;  // RNE
  return (unsigned short)r;
}
__device__ __forceinline__ float bf2f(unsigned short s) {
  return __uint_as_float(((unsigned int)s) << 16);
}
__device__ __forceinline__ float fast_tanh(float x) {
  float t = __expf(2.0f * x);
  return fmaf(-2.0f, __builtin_amdgcn_rcpf(t + 1.0f), 1.0f);
}

// ---- prep: split fp32 -> bf16 hi + bf16 lo (optionally pre-scaled) ----
__global__ void split_kernel(const float* __restrict__ src,
                             unsigned short* __restrict__ hi,
                             unsigned short* __restrict__ lo,
                             int n, float scale) {
  int i = blockIdx.x * 256 + threadIdx.x;
  if (i < n) {
    float v = src[i] * scale;
    unsigned short h = f2bf(v);
    hi[i] = h;
    lo[i] = f2bf(v - bf2f(h));
  }
}

// ---- drive GEMM: drive = x@W^T + b (fp32 out) ----
__global__ __launch_bounds__(256) void drive_kernel(
    const float* __restrict__ x, const unsigned short* __restrict__ Whi,
    const unsigned short* __restrict__ Wlo, const float* __restrict__ bias,
    float* __restrict__ drive) {
  __shared__ __align__(16) unsigned short Ah[128][40];
  __shared__ __align__(16) unsigned short Al[128][40];
  __shared__ __align__(16) unsigned short Bh[128][40];
  __shared__ __align__(16) unsigned short Bl[128][40];

  const int t = threadIdx.x;
  const int bm = blockIdx.y, bn = blockIdx.x;
  const int row = t >> 1, half = t & 1;
  const int lane = t & 63, wave = t >> 6;
  const int wm = wave >> 1, wn = wave & 1;
  const int quad = lane >> 4, l16 = lane & 15;

  f32x4 acc[4][4] = {};

  const float* xp = x + (size_t)(bm * 128 + row) * M_DIM + half * 16;
  const unsigned short* wh = Whi + (size_t)(bn * 128 + row) * M_DIM + half * 16;
  const unsigned short* wl = Wlo + (size_t)(bn * 128 + row) * M_DIM + half * 16;

  for (int k0 = 0; k0 < M_DIM; k0 += 32) {
    float4 v[4];
#pragma unroll
    for (int q = 0; q < 4; ++q) v[q] = *(const float4*)(xp + k0 + 4 * q);
    unsigned short hiv[16], lov[16];
#pragma unroll
    for (int q = 0; q < 4; ++q) {
      float fv[4] = {v[q].x, v[q].y, v[q].z, v[q].w};
#pragma unroll
      for (int e = 0; e < 4; ++e) {
        unsigned short h = f2bf(fv[e]);
        hiv[4 * q + e] = h;
        lov[4 * q + e] = f2bf(fv[e] - bf2f(h));
      }
    }
    *(uint4*)&Ah[row][half * 16]     = *(uint4*)&hiv[0];
    *(uint4*)&Ah[row][half * 16 + 8] = *(uint4*)&hiv[8];
    *(uint4*)&Al[row][half * 16]     = *(uint4*)&lov[0];
    *(uint4*)&Al[row][half * 16 + 8] = *(uint4*)&lov[8];
    *(uint4*)&Bh[row][half * 16]     = *(const uint4*)(wh + k0);
    *(uint4*)&Bh[row][half * 16 + 8] = *(const uint4*)(wh + k0 + 8);
    *(uint4*)&Bl[row][half * 16]     = *(const uint4*)(wl + k0);
    *(uint4*)&Bl[row][half * 16 + 8] = *(const uint4*)(wl + k0 + 8);
    __syncthreads();

    bf16x8 ah[4], al[4], bh[4], bl[4];
#pragma unroll
    for (int i = 0; i < 4; ++i) {
      ah[i] = *(const bf16x8*)&Ah[wm * 64 + i * 16 + l16][quad * 8];
      al[i] = *(const bf16x8*)&Al[wm * 64 + i * 16 + l16][quad * 8];
    }
#pragma unroll
    for (int j = 0; j < 4; ++j) {
      bh[j] = *(const bf16x8*)&Bh[wn * 64 + j * 16 + l16][quad * 8];
      bl[j] = *(const bf16x8*)&Bl[wn * 64 + j * 16 + l16][quad * 8];
    }
#pragma unroll
    for (int i = 0; i < 4; ++i)
#pragma unroll
      for (int j = 0; j < 4; ++j) {
        acc[i][j] = __builtin_amdgcn_mfma_f32_16x16x32_bf16(ah[i], bh[j], acc[i][j], 0, 0, 0);
        acc[i][j] = __builtin_amdgcn_mfma_f32_16x16x32_bf16(ah[i], bl[j], acc[i][j], 0, 0, 0);
        acc[i][j] = __builtin_amdgcn_mfma_f32_16x16x32_bf16(al[i], bh[j], acc[i][j], 0, 0, 0);
      }
    __syncthreads();
  }

#pragma unroll
  for (int i = 0; i < 4; ++i)
#pragma unroll
    for (int j = 0; j < 4; ++j) {
      int gcol = bn * 128 + wn * 64 + j * 16 + l16;
      float bv = bias[gcol];
#pragma unroll
      for (int r = 0; r < 4; ++r) {
        int grow = bm * 128 + wm * 64 + i * 16 + quad * 4 + r;
        drive[(size_t)grow * A_DIM + gcol] = acc[i][j][r] + bv;
      }
    }
}

// ---- fused settling loop: 9 recurrent steps, sigma LDS-resident ----
// Block: 64 rows, 512 threads (8 waves). Wave w owns cols [w*64, w*64+64).
// sigma: TWO ping-pong LDS buffers (128KB total -> 1 block/CU -> 256-VGPR
// budget). Layout per buffer: row stride 512 bf16; granule (8 bf16 = 16B) g
// stored at slot g ^ (r&7) -> conflict-free ds_read_b128 A-fragments.
// J (hi/lo, 1MB, L2-resident) read per-lane into B-fragments via 32-bit
// element offsets + SGPR base; per kb both 64B halves of every touched 128B
// line load adjacently, all 16 loads before the MFMA cluster.
__attribute__((amdgpu_waves_per_eu(2, 2)))
__global__ __launch_bounds__(512) void settle_kernel(
    const unsigned short* __restrict__ Jhi,
    const unsigned short* __restrict__ Jlo,
    const float* __restrict__ drive, float* __restrict__ outf) {
  __shared__ __align__(16) unsigned short smem[2][64 * 512];  // 128 KB

  const int t = threadIdx.x;
  const int lane = t & 63, w = t >> 6;
  const int quad = lane >> 4, l16 = lane & 15;
  const int r0 = blockIdx.x * 64;

  // drive -> registers in MFMA C/D layout (row = i*16+quad*4+rr, col = w*64+j*16+l16)
  float dreg[4][4][4];
#pragma unroll
  for (int i = 0; i < 4; ++i)
#pragma unroll
    for (int j = 0; j < 4; ++j) {
      const float* dp =
          drive + (size_t)(r0 + i * 16 + quad * 4) * A_DIM + w * 64 + j * 16 + l16;
#pragma unroll
      for (int rr = 0; rr < 4; ++rr) dreg[i][j][rr] = dp[(size_t)rr * A_DIM];
    }

  // sigma1 = tanh(drive) -> buffer 0 (swizzled scalar b16 writes)
#pragma unroll
  for (int i = 0; i < 4; ++i)
#pragma unroll
    for (int rr = 0; rr < 4; ++rr) {
      const int r = i * 16 + quad * 4 + rr;
#pragma unroll
      for (int j = 0; j < 4; ++j) {
        const int c = w * 64 + j * 16 + l16;
        smem[0][r * 512 + (((c >> 3) ^ (r & 7)) << 3) + (c & 7)] =
            f2bf(fast_tanh(dreg[i][j][rr]));
      }
    }

  // per-lane J row offsets (32-bit, element units) against SGPR bases Jhi/Jlo
  unsigned joff[4];
#pragma unroll
  for (int j = 0; j < 4; ++j)
    joff[j] = (unsigned)((w * 64 + j * 16 + l16) * A_DIM + quad * 8);

  // A-fragment LDS offsets (bf16 units); kb adds kb*64 (XOR stays in low 3 bits)
  int abase[4][2];
#pragma unroll
  for (int i = 0; i < 4; ++i) {
    const int r = i * 16 + l16;
#pragma unroll
    for (int h = 0; h < 2; ++h)
      abase[i][h] = r * 512 + (((h * 4 + quad) ^ (r & 7)) << 3);
  }

  __syncthreads();

  for (int s = 0; s < 9; ++s) {
    const unsigned short* rd = smem[s & 1];
    unsigned short* wr = (unsigned short*)smem[(s & 1) ^ 1];
    f32x4 acc[4][4] = {};
    for (int kb = 0; kb < 8; ++kb) {
      const int k0 = kb * 64;
      bf16x8 a0[4], a1[4], bh0[4], bh1[4], bl0[4], bl1[4];
      // A fragments (LDS, lgkmcnt domain)
#pragma unroll
      for (int i = 0; i < 4; ++i) {
        a0[i] = *(const bf16x8*)&rd[abase[i][0] + k0];
        a1[i] = *(const bf16x8*)&rd[abase[i][1] + k0];
      }
      // ALL J global loads up front (vmcnt domain): 16 loads in flight while
      // the hi-MFMA cluster (~320cy) runs -> covers ~200cy L2 latency.
#pragma unroll
      for (int j = 0; j < 4; ++j) {
        bh0[j] = *(const bf16x8*)(Jhi + joff[j] + k0);
        bh1[j] = *(const bf16x8*)(Jhi + joff[j] + k0 + 32);
      }
#pragma unroll
      for (int j = 0; j < 4; ++j) {
        bl0[j] = *(const bf16x8*)(Jlo + joff[j] + k0);
        bl1[j] = *(const bf16x8*)(Jlo + joff[j] + k0 + 32);
      }
#pragma unroll
      for (int i = 0; i < 4; ++i)
#pragma unroll
        for (int j = 0; j < 4; ++j) {
          acc[i][j] = __builtin_amdgcn_mfma_f32_16x16x32_bf16(a0[i], bh0[j], acc[i][j], 0, 0, 0);
          acc[i][j] = __builtin_amdgcn_mfma_f32_16x16x32_bf16(a1[i], bh1[j], acc[i][j], 0, 0, 0);
        }
#pragma unroll
      for (int i = 0; i < 4; ++i)
#pragma unroll
        for (int j = 0; j < 4; ++j) {
          acc[i][j] = __builtin_amdgcn_mfma_f32_16x16x32_bf16(a0[i], bl0[j], acc[i][j], 0, 0, 0);
          acc[i][j] = __builtin_amdgcn_mfma_f32_16x16x32_bf16(a1[i], bl1[j], acc[i][j], 0, 0, 0);
        }
    }

    if (s == 8) {  // final step: fp32 out, no sigma rewrite
#pragma unroll
      for (int i = 0; i < 4; ++i)
#pragma unroll
        for (int j = 0; j < 4; ++j) {
          float* op =
              outf + (size_t)(r0 + i * 16 + quad * 4) * A_DIM + w * 64 + j * 16 + l16;
#pragma unroll
          for (int rr = 0; rr < 4; ++rr)
            op[(size_t)rr * A_DIM] = fast_tanh(dreg[i][j][rr] + acc[i][j][rr]);
        }
    } else {
      // write new sigma into the IDLE buffer: no pre-write barrier needed
#pragma unroll
      for (int i = 0; i < 4; ++i)
#pragma unroll
        for (int rr = 0; rr < 4; ++rr) {
          const int r = i * 16 + quad * 4 + rr;
#pragma unroll
          for (int j = 0; j < 4; ++j) {
            const int c = w * 64 + j * 16 + l16;
            wr[r * 512 + (((c >> 3) ^ (r & 7)) << 3) + (c & 7)] =
                f2bf(fast_tanh(dreg[i][j][rr] + acc[i][j][rr]));
          }
        }
      __syncthreads();  // writes visible; all waves done with old buffer
    }
  }
}

extern "C" void kernel_launch(void* const* d_in, const int* in_sizes, int n_in,
                              void* d_out, int out_size, void* d_ws, size_t ws_size,
                              hipStream_t stream) {
  const float* x = (const float*)d_in[0];
  const float* W = (const float*)d_in[1];
  const float* b = (const float*)d_in[2];
  const float* J = (const float*)d_in[3];
  float* out = (float*)d_out;

  char* ws = (char*)d_ws;
  float* drive        = (float*)(ws);                       // 33,554,432 B
  unsigned short* Whi = (unsigned short*)(ws + 33554432);   //  1,048,576 B
  unsigned short* Wlo = (unsigned short*)(ws + 34603008);   //  1,048,576 B
  unsigned short* Jhi = (unsigned short*)(ws + 35651584);   //    524,288 B
  unsigned short* Jlo = (unsigned short*)(ws + 36175872);   // end: 36,700,160

  const int nW = A_DIM * M_DIM;
  const int nJ = A_DIM * A_DIM;
  split_kernel<<<(nW + 255) / 256, 256, 0, stream>>>(W, Whi, Wlo, nW, 1.0f);
  split_kernel<<<(nJ + 255) / 256, 256, 0, stream>>>(J, Jhi, Jlo, nJ, 10.0f);

  dim3 dgrid(A_DIM / 128, B_DIM / 128);  // (4, 128)
  drive_kernel<<<dgrid, 256, 0, stream>>>(x, Whi, Wlo, b, drive);

  settle_kernel<<<B_DIM / 64, 512, 0, stream>>>(Jhi, Jlo, drive, out);
}

// Round 5
// 984.392 us; speedup vs baseline: 1.0734x; 1.0734x over previous
//
#include <hip/hip_runtime.h>
#include <stdint.h>

// AttractorDynamics: sigma = iterate(tanh(drive + (sigma @ J^T)/tau), 10)
// B=16384, M=1024, A=512, tau=0.1, sigma0=0.
// R7: DESIGN FOR the 128-VGPR budget instead of fighting the allocator.
//  - R4/R5/R6: launch_bounds(512,2), waves_per_eu(2,2), and 128KB-LDS
//    occupancy forcing ALL failed to move VGPR_Count off 128; FETCH 1.2GB
//    matched dreg scratch re-reads exactly. Allocator always targets 128.
//  - New settle structure: 1024 threads / 16 waves, wave tile 64 rows x 32
//    cols. Hot live set: acc 32 + A-frags 32 + J-frags 32 (hi then lo,
//    sequenced) + addr ~20 = ~116 < 128. No dreg: drive re-read from
//    L2-resident slice (128KB/block) in each step epilogue.
//  - sigma double-buffered in LDS (128KB, 1 block/CU, one barrier/step).
// drive_kernel / split_kernel unchanged.

#define B_DIM 16384
#define M_DIM 1024
#define A_DIM 512

typedef short bf16x8 __attribute__((ext_vector_type(8)));
typedef float f32x4 __attribute__((ext_vector_type(4)));

__device__ __forceinline__ unsigned short f2bf(float f) {
  unsigned int u = __float_as_uint(f);
  unsigned int r = (u + 0x7FFFu + ((u >> 16) & 1u)) >> 16;  // RNE
  return (unsigned short)r;
}
__device__ __forceinline__ float bf2f(unsigned short s) {
  return __uint_as_float(((unsigned int)s) << 16);
}
__device__ __forceinline__ float fast_tanh(float x) {
  float t = __expf(2.0f * x);
  return fmaf(-2.0f, __builtin_amdgcn_rcpf(t + 1.0f), 1.0f);
}

// ---- prep: split fp32 -> bf16 hi + bf16 lo (optionally pre-scaled) ----
__global__ void split_kernel(const float* __restrict__ src,
                             unsigned short* __restrict__ hi,
                             unsigned short* __restrict__ lo,
                             int n, float scale) {
  int i = blockIdx.x * 256 + threadIdx.x;
  if (i < n) {
    float v = src[i] * scale;
    unsigned short h = f2bf(v);
    hi[i] = h;
    lo[i] = f2bf(v - bf2f(h));
  }
}

// ---- drive GEMM: drive = x@W^T + b (fp32 out) ----
__global__ __launch_bounds__(256) void drive_kernel(
    const float* __restrict__ x, const unsigned short* __restrict__ Whi,
    const unsigned short* __restrict__ Wlo, const float* __restrict__ bias,
    float* __restrict__ drive) {
  __shared__ __align__(16) unsigned short Ah[128][40];
  __shared__ __align__(16) unsigned short Al[128][40];
  __shared__ __align__(16) unsigned short Bh[128][40];
  __shared__ __align__(16) unsigned short Bl[128][40];

  const int t = threadIdx.x;
  const int bm = blockIdx.y, bn = blockIdx.x;
  const int row = t >> 1, half = t & 1;
  const int lane = t & 63, wave = t >> 6;
  const int wm = wave >> 1, wn = wave & 1;
  const int quad = lane >> 4, l16 = lane & 15;

  f32x4 acc[4][4] = {};

  const float* xp = x + (size_t)(bm * 128 + row) * M_DIM + half * 16;
  const unsigned short* wh = Whi + (size_t)(bn * 128 + row) * M_DIM + half * 16;
  const unsigned short* wl = Wlo + (size_t)(bn * 128 + row) * M_DIM + half * 16;

  for (int k0 = 0; k0 < M_DIM; k0 += 32) {
    float4 v[4];
#pragma unroll
    for (int q = 0; q < 4; ++q) v[q] = *(const float4*)(xp + k0 + 4 * q);
    unsigned short hiv[16], lov[16];
#pragma unroll
    for (int q = 0; q < 4; ++q) {
      float fv[4] = {v[q].x, v[q].y, v[q].z, v[q].w};
#pragma unroll
      for (int e = 0; e < 4; ++e) {
        unsigned short h = f2bf(fv[e]);
        hiv[4 * q + e] = h;
        lov[4 * q + e] = f2bf(fv[e] - bf2f(h));
      }
    }
    *(uint4*)&Ah[row][half * 16]     = *(uint4*)&hiv[0];
    *(uint4*)&Ah[row][half * 16 + 8] = *(uint4*)&hiv[8];
    *(uint4*)&Al[row][half * 16]     = *(uint4*)&lov[0];
    *(uint4*)&Al[row][half * 16 + 8] = *(uint4*)&lov[8];
    *(uint4*)&Bh[row][half * 16]     = *(const uint4*)(wh + k0);
    *(uint4*)&Bh[row][half * 16 + 8] = *(const uint4*)(wh + k0 + 8);
    *(uint4*)&Bl[row][half * 16]     = *(const uint4*)(wl + k0);
    *(uint4*)&Bl[row][half * 16 + 8] = *(const uint4*)(wl + k0 + 8);
    __syncthreads();

    bf16x8 ah[4], al[4], bh[4], bl[4];
#pragma unroll
    for (int i = 0; i < 4; ++i) {
      ah[i] = *(const bf16x8*)&Ah[wm * 64 + i * 16 + l16][quad * 8];
      al[i] = *(const bf16x8*)&Al[wm * 64 + i * 16 + l16][quad * 8];
    }
#pragma unroll
    for (int j = 0; j < 4; ++j) {
      bh[j] = *(const bf16x8*)&Bh[wn * 64 + j * 16 + l16][quad * 8];
      bl[j] = *(const bf16x8*)&Bl[wn * 64 + j * 16 + l16][quad * 8];
    }
#pragma unroll
    for (int i = 0; i < 4; ++i)
#pragma unroll
      for (int j = 0; j < 4; ++j) {
        acc[i][j] = __builtin_amdgcn_mfma_f32_16x16x32_bf16(ah[i], bh[j], acc[i][j], 0, 0, 0);
        acc[i][j] = __builtin_amdgcn_mfma_f32_16x16x32_bf16(ah[i], bl[j], acc[i][j], 0, 0, 0);
        acc[i][j] = __builtin_amdgcn_mfma_f32_16x16x32_bf16(al[i], bh[j], acc[i][j], 0, 0, 0);
      }
    __syncthreads();
  }

#pragma unroll
  for (int i = 0; i < 4; ++i)
#pragma unroll
    for (int j = 0; j < 4; ++j) {
      int gcol = bn * 128 + wn * 64 + j * 16 + l16;
      float bv = bias[gcol];
#pragma unroll
      for (int r = 0; r < 4; ++r) {
        int grow = bm * 128 + wm * 64 + i * 16 + quad * 4 + r;
        drive[(size_t)grow * A_DIM + gcol] = acc[i][j][r] + bv;
      }
    }
}

// ---- fused settling loop: 9 recurrent steps, sigma LDS-resident ----
// Block: 64 rows, 1024 threads (16 waves, 4/EU). Wave w owns cols
// [w*32, w*32+32). sigma: two ping-pong LDS buffers (128KB -> 1 block/CU,
// one barrier/step). Per buffer: row stride 512 bf16; granule (8 bf16=16B)
// g stored at slot g ^ (r&7) -> conflict-free ds_read_b128 A-fragments.
// J (hi/lo, 1MB, L2-resident) read per-lane into B-fragments; hi then lo
// SEQUENCED so only 32 J VGPRs are live at a time. drive re-read from L2
// in each epilogue (no dreg). Hot live set ~116 VGPR < 128.
__global__ __launch_bounds__(1024) void settle_kernel(
    const unsigned short* __restrict__ Jhi,
    const unsigned short* __restrict__ Jlo,
    const float* __restrict__ drive, float* __restrict__ outf) {
  __shared__ __align__(16) unsigned short smem[2][64 * 512];  // 128 KB

  const int t = threadIdx.x;
  const int lane = t & 63, w = t >> 6;  // w in 0..15
  const int quad = lane >> 4, l16 = lane & 15;
  const int r0 = blockIdx.x * 64;

  // prologue: sigma1 = tanh(drive) -> buffer 0
#pragma unroll
  for (int i = 0; i < 4; ++i)
#pragma unroll
    for (int rr = 0; rr < 4; ++rr) {
      const int r = i * 16 + quad * 4 + rr;
#pragma unroll
      for (int j = 0; j < 2; ++j) {
        const int c = w * 32 + j * 16 + l16;
        smem[0][r * 512 + (((c >> 3) ^ (r & 7)) << 3) + (c & 7)] =
            f2bf(fast_tanh(drive[(size_t)(r0 + r) * A_DIM + c]));
      }
    }

  // per-lane J row offsets (32-bit, element units) against SGPR bases
  unsigned joff[2];
#pragma unroll
  for (int j = 0; j < 2; ++j)
    joff[j] = (unsigned)((w * 32 + j * 16 + l16) * A_DIM + quad * 8);

  // A-fragment LDS offsets (bf16 units); kb adds kb*64 (XOR stays in low 3 bits)
  int abase[4][2];
#pragma unroll
  for (int i = 0; i < 4; ++i) {
    const int r = i * 16 + l16;
#pragma unroll
    for (int h = 0; h < 2; ++h)
      abase[i][h] = r * 512 + (((h * 4 + quad) ^ (r & 7)) << 3);
  }

  __syncthreads();

  for (int s = 0; s < 9; ++s) {
    const unsigned short* rdb = smem[s & 1];
    unsigned short* wrb = (unsigned short*)smem[(s & 1) ^ 1];
    f32x4 acc[4][2] = {};
    for (int kb = 0; kb < 8; ++kb) {
      const int k0 = kb * 64;
      bf16x8 a0[4], a1[4], bh0[2], bh1[2];
      // J hi loads first (vmcnt domain), then A fragments (lgkmcnt domain)
#pragma unroll
      for (int j = 0; j < 2; ++j) {
        bh0[j] = *(const bf16x8*)(Jhi + joff[j] + k0);
        bh1[j] = *(const bf16x8*)(Jhi + joff[j] + k0 + 32);
      }
#pragma unroll
      for (int i = 0; i < 4; ++i) {
        a0[i] = *(const bf16x8*)&rdb[abase[i][0] + k0];
        a1[i] = *(const bf16x8*)&rdb[abase[i][1] + k0];
      }
#pragma unroll
      for (int i = 0; i < 4; ++i)
#pragma unroll
        for (int j = 0; j < 2; ++j) {
          acc[i][j] = __builtin_amdgcn_mfma_f32_16x16x32_bf16(a0[i], bh0[j], acc[i][j], 0, 0, 0);
          acc[i][j] = __builtin_amdgcn_mfma_f32_16x16x32_bf16(a1[i], bh1[j], acc[i][j], 0, 0, 0);
        }
      // J lo loads AFTER hi MFMAs: J live stays at 32 regs; 4 waves/SIMD
      // TLP covers the L2 latency.
      bf16x8 bl0[2], bl1[2];
#pragma unroll
      for (int j = 0; j < 2; ++j) {
        bl0[j] = *(const bf16x8*)(Jlo + joff[j] + k0);
        bl1[j] = *(const bf16x8*)(Jlo + joff[j] + k0 + 32);
      }
#pragma unroll
      for (int i = 0; i < 4; ++i)
#pragma unroll
        for (int j = 0; j < 2; ++j) {
          acc[i][j] = __builtin_amdgcn_mfma_f32_16x16x32_bf16(a0[i], bl0[j], acc[i][j], 0, 0, 0);
          acc[i][j] = __builtin_amdgcn_mfma_f32_16x16x32_bf16(a1[i], bl1[j], acc[i][j], 0, 0, 0);
        }
    }

    if (s == 8) {  // final step: fp32 out, drive re-read from L2
#pragma unroll
      for (int i = 0; i < 4; ++i)
#pragma unroll
        for (int j = 0; j < 2; ++j) {
          const int c = w * 32 + j * 16 + l16;
          const size_t base = (size_t)(r0 + i * 16 + quad * 4) * A_DIM + c;
#pragma unroll
          for (int rr = 0; rr < 4; ++rr)
            outf[base + (size_t)rr * A_DIM] =
                fast_tanh(drive[base + (size_t)rr * A_DIM] + acc[i][j][rr]);
        }
    } else {
      // write new sigma into the IDLE buffer (no pre-write barrier needed)
#pragma unroll
      for (int i = 0; i < 4; ++i)
#pragma unroll
        for (int j = 0; j < 2; ++j) {
          const int c = w * 32 + j * 16 + l16;
#pragma unroll
          for (int rr = 0; rr < 4; ++rr) {
            const int r = i * 16 + quad * 4 + rr;
            const float dv = drive[(size_t)(r0 + r) * A_DIM + c];
            wrb[r * 512 + (((c >> 3) ^ (r & 7)) << 3) + (c & 7)] =
                f2bf(fast_tanh(dv + acc[i][j][rr]));
          }
        }
      __syncthreads();  // writes visible; all waves done with old buffer
    }
  }
}

extern "C" void kernel_launch(void* const* d_in, const int* in_sizes, int n_in,
                              void* d_out, int out_size, void* d_ws, size_t ws_size,
                              hipStream_t stream) {
  const float* x = (const float*)d_in[0];
  const float* W = (const float*)d_in[1];
  const float* b = (const float*)d_in[2];
  const float* J = (const float*)d_in[3];
  float* out = (float*)d_out;

  char* ws = (char*)d_ws;
  float* drive        = (float*)(ws);                       // 33,554,432 B
  unsigned short* Whi = (unsigned short*)(ws + 33554432);   //  1,048,576 B
  unsigned short* Wlo = (unsigned short*)(ws + 34603008);   //  1,048,576 B
  unsigned short* Jhi = (unsigned short*)(ws + 35651584);   //    524,288 B
  unsigned short* Jlo = (unsigned short*)(ws + 36175872);   // end: 36,700,160

  const int nW = A_DIM * M_DIM;
  const int nJ = A_DIM * A_DIM;
  split_kernel<<<(nW + 255) / 256, 256, 0, stream>>>(W, Whi, Wlo, nW, 1.0f);
  split_kernel<<<(nJ + 255) / 256, 256, 0, stream>>>(J, Jhi, Jlo, nJ, 10.0f);

  dim3 dgrid(A_DIM / 128, B_DIM / 128);  // (4, 128)
  drive_kernel<<<dgrid, 256, 0, stream>>>(x, Whi, Wlo, b, drive);

  settle_kernel<<<B_DIM / 64, 1024, 0, stream>>>(Jhi, Jlo, drive, out);
}